// Round 2
// baseline (338.924 us; speedup 1.0000x reference)
//
#include <hip/hip_runtime.h>

#define SEQS_PER_WG 8
#define HID 128
#define NF 13
#define SLEN 128
#define NSEQ 2048
#define ZSTRIDE 232   // f16 elems per z row; 232*2=464B rows (16B aligned)

typedef _Float16 half8 __attribute__((ext_vector_type(8)));
typedef float floatx4 __attribute__((ext_vector_type(4)));

__device__ __forceinline__ float fast_rcp(float x) { return __builtin_amdgcn_rcpf(x); }
__device__ __forceinline__ float sigm(float x)  { return fast_rcp(1.0f + __expf(-x)); }
__device__ __forceinline__ float tanh_(float x) { return 1.0f - 2.0f * fast_rcp(1.0f + __expf(2.0f * x)); }

// v_permlane32_swap_b32: first.row1 <-> second.row0 (rows = 32-lane halves).
// pr[0] = {row0: a's lanes 0-31 (unchanged), row1: b's lanes 0-31 (moved up)}.
// This IS "hi ? (lane-32's b) : (own a)" in one full-rate VALU op (no LDS).
__device__ __forceinline__ float rowmerge(float a, float b) {
    auto pr = __builtin_amdgcn_permlane32_swap(__float_as_int(a), __float_as_int(b),
                                               false, false);
    return __int_as_float(pr[0]);
}

__global__ __launch_bounds__(512, 2)
void lstm_encdec_kernel(const float* __restrict__ X,
                        const float* __restrict__ W_ih,
                        const float* __restrict__ W_hh,
                        const float* __restrict__ b_ih,
                        const float* __restrict__ b_hh,
                        const float* __restrict__ W_fc,
                        const float* __restrict__ b_fc,
                        float* __restrict__ out)
{
    // z = [h (128) | x (13, padded to 32)] per seq slot, fp16, double-buffered.
    // 16 row slots (A-operand reads rows 0..15); rows 8..15 stay zero.
    __shared__ _Float16 zbuf[2][16 * ZSTRIDE];

    const int tid  = threadIdx.x;
    const int wave = tid >> 6;            // 0..7
    const int lane = tid & 63;
    const int quad = lane >> 4;           // 0..3
    const int lcol = lane & 15;
    const int row0 = (quad & 1) * 4 + ((quad >> 1) ? 2 : 0); // first of 2 seq rows owned
    const int unit = wave * 16 + lcol;                       // hidden unit 0..127
    const int seq0 = blockIdx.x * SEQS_PER_WG;

    // ---- loop-invariant B fragments: gates[s][n] = sum_k z[s][k]*W[n][k], n = g*128+unit
    half8 Bf[4][5];
    floatx4 biasv[4];
    #pragma unroll
    for (int g = 0; g < 4; ++g) {
        const int n = g * HID + unit;
        #pragma unroll
        for (int ks = 0; ks < 4; ++ks) {              // h part
            const float* p = W_hh + n * HID + ks * 32 + quad * 8;
            half8 v;
            #pragma unroll
            for (int j = 0; j < 8; ++j) v[j] = (_Float16)p[j];
            Bf[g][ks] = v;
        }
        {                                             // x part (K-step 4)
            half8 v;
            #pragma unroll
            for (int j = 0; j < 8; ++j) {
                int kk = quad * 8 + j;
                v[j] = (kk < NF) ? (_Float16)W_ih[n * NF + kk] : (_Float16)0.0f;
            }
            Bf[g][4] = v;
        }
        float b = b_ih[n] + b_hh[n];
        biasv[g] = (floatx4){b, b, b, b};             // first MFMA's C operand
    }

    // W_fc fragments (wave 0 only)
    half8 Wfcf[4];
    floatx4 bfcv = (floatx4){0.0f, 0.0f, 0.0f, 0.0f};
    if (wave == 0) {
        #pragma unroll
        for (int ks = 0; ks < 4; ++ks) {
            half8 v;
            #pragma unroll
            for (int j = 0; j < 8; ++j)
                v[j] = (lcol < NF) ? (_Float16)W_fc[lcol * HID + ks * 32 + quad * 8 + j]
                                   : (_Float16)0.0f;
            Wfcf[ks] = v;
        }
        float b = (lcol < NF) ? b_fc[lcol] : 0.0f;
        bfcv = (floatx4){b, b, b, b};
    }

    // ---- init LDS: zero both buffers, then x_0
    for (int i = tid; i < 2 * 16 * ZSTRIDE; i += 512)
        ((_Float16*)zbuf)[i] = (_Float16)0.0f;
    __syncthreads();

    const bool xact = tid < SEQS_PER_WG * NF;         // 104 threads load x
    const int  xs = tid / NF, xf = tid % NF;
    const long xbase = (long)(seq0 + xs) * SLEN * NF + xf;
    if (xact) zbuf[0][xs * ZSTRIDE + HID + xf] = (_Float16)X[xbase];
    __syncthreads();

    float creg[2] = {0.0f, 0.0f};
    float h0 = 0.0f, h1 = 0.0f;
    int p = 0;

#define GATE_MFMA(NKS, ZR)                                                     \
    half8 a[5];                                                                \
    _Pragma("unroll")                                                          \
    for (int ks = 0; ks < (NKS); ++ks)                                         \
        a[ks] = *(const half8*)&(ZR)[lcol * ZSTRIDE + ks * 32 + quad * 8];     \
    floatx4 acc[4];                                                            \
    _Pragma("unroll")                                                          \
    for (int g = 0; g < 4; ++g)                                                \
        acc[g] = __builtin_amdgcn_mfma_f32_16x16x32_f16(a[0], Bf[g][0],        \
                                                        biasv[g], 0, 0, 0);    \
    _Pragma("unroll")                                                          \
    for (int ks = 1; ks < (NKS); ++ks)                                         \
        _Pragma("unroll")                                                      \
        for (int g = 0; g < 4; ++g)                                            \
            acc[g] = __builtin_amdgcn_mfma_f32_16x16x32_f16(a[ks], Bf[g][ks],  \
                                                            acc[g], 0, 0, 0);

#define GATES_EPILOGUE(ZW)                                                     \
    {                                                                          \
        float gv0[4], gv1[4];                                                  \
        _Pragma("unroll")                                                      \
        for (int g = 0; g < 4; ++g) {                                          \
            gv0[g] = rowmerge(acc[g][0], acc[g][2]);                           \
            gv1[g] = rowmerge(acc[g][1], acc[g][3]);                           \
        }                                                                      \
        float c0 = sigm(gv0[1]) * creg[0] + sigm(gv0[0]) * tanh_(gv0[2]);      \
        creg[0] = c0;                                                          \
        h0 = sigm(gv0[3]) * tanh_(c0);                                         \
        float c1 = sigm(gv1[1]) * creg[1] + sigm(gv1[0]) * tanh_(gv1[2]);      \
        creg[1] = c1;                                                          \
        h1 = sigm(gv1[3]) * tanh_(c1);                                         \
        (ZW)[(row0 + 0) * ZSTRIDE + unit] = (_Float16)h0;                      \
        (ZW)[(row0 + 1) * ZSTRIDE + unit] = (_Float16)h1;                      \
    }

    // ===================== encoder: 128 steps, 1 barrier/step =====================
    for (int t = 0; t < SLEN; ++t) {
        const int tn = (t + 1 < SLEN) ? t + 1 : SLEN - 1;
        float xpre = 0.0f;
        if (xact) xpre = X[xbase + tn * NF];

        const _Float16* zr = zbuf[p];
        _Float16* zw = zbuf[1 - p];

        GATE_MFMA(5, zr)
        GATES_EPILOGUE(zw)
        if (xact) zw[xs * ZSTRIDE + HID + xf] = (_Float16)xpre;

        __syncthreads();
        p ^= 1;
    }

    // embeddings = h_n
    out[(long)(seq0 + row0 + 0) * HID + unit] = h0;
    out[(long)(seq0 + row0 + 1) * HID + unit] = h1;

    float* dec = out + (long)NSEQ * HID;

    // ===================== decoder step 0: uses real x_127 (5 K-steps) ============
    {
        const _Float16* zr = zbuf[p];
        _Float16* zw = zbuf[1 - p];
        GATE_MFMA(5, zr)
        GATES_EPILOGUE(zw)
        __syncthreads();
        p ^= 1;
    }

    // ---- rebuild Bf[g][0..3] <- W_eff = W_hh + W_ih @ W_fc, biasv <- b_eff ----
    // (decoder recurrence for t>=1 never needs x: x_{t+1} = h_{t+1}@W_fc^T + b_fc
    //  folds into gates = h @ W_eff^T + b_eff)
    #pragma unroll
    for (int g = 0; g < 4; ++g) {
        const int n = g * HID + unit;
        float wih[NF];
        #pragma unroll
        for (int f = 0; f < NF; ++f) wih[f] = W_ih[n * NF + f];
        #pragma unroll
        for (int ks = 0; ks < 4; ++ks) {
            half8 v;
            #pragma unroll
            for (int j = 0; j < 8; ++j) {
                const int k = ks * 32 + quad * 8 + j;
                float s = W_hh[n * HID + k];
                #pragma unroll
                for (int f = 0; f < NF; ++f) s += wih[f] * W_fc[f * HID + k];
                v[j] = (_Float16)s;
            }
            Bf[g][ks] = v;
        }
        float bb = b_ih[n] + b_hh[n];
        #pragma unroll
        for (int f = 0; f < NF; ++f) bb += wih[f] * b_fc[f];
        biasv[g] = (floatx4){bb, bb, bb, bb};
    }

    // ============ decoder steps 1..127: 4 K-steps, 1 barrier, FC overlapped =======
    for (int t = 1; t < SLEN; ++t) {
        const _Float16* zr = zbuf[p];
        _Float16* zw = zbuf[1 - p];

        GATE_MFMA(4, zr)

        // wave 0: dec output for step t-1 = FC(h_t); h_t IS a[0..3] (reuse, no LDS)
        if (wave == 0) {
            floatx4 o = bfcv;
            #pragma unroll
            for (int ks = 0; ks < 4; ++ks)
                o = __builtin_amdgcn_mfma_f32_16x16x32_f16(a[ks], Wfcf[ks], o, 0, 0, 0);
            if (quad < 2 && lcol < NF) {
                #pragma unroll
                for (int r = 0; r < 4; ++r)
                    dec[(long)(seq0 + quad * 4 + r) * SLEN * NF + (t - 1) * NF + lcol] = o[r];
            }
        }

        GATES_EPILOGUE(zw)

        __syncthreads();
        p ^= 1;
    }

    // ---- final dec output: FC(h_128) from the last written buffer ----
    if (wave == 0) {
        const _Float16* zr = zbuf[p];
        half8 af[4];
        #pragma unroll
        for (int ks = 0; ks < 4; ++ks)
            af[ks] = *(const half8*)&zr[lcol * ZSTRIDE + ks * 32 + quad * 8];
        floatx4 o = bfcv;
        #pragma unroll
        for (int ks = 0; ks < 4; ++ks)
            o = __builtin_amdgcn_mfma_f32_16x16x32_f16(af[ks], Wfcf[ks], o, 0, 0, 0);
        if (quad < 2 && lcol < NF) {
            #pragma unroll
            for (int r = 0; r < 4; ++r)
                dec[(long)(seq0 + quad * 4 + r) * SLEN * NF + (SLEN - 1) * NF + lcol] = o[r];
        }
    }
}

extern "C" void kernel_launch(void* const* d_in, const int* in_sizes, int n_in,
                              void* d_out, int out_size, void* d_ws, size_t ws_size,
                              hipStream_t stream) {
    const float* X    = (const float*)d_in[0];
    const float* W_ih = (const float*)d_in[1];
    const float* W_hh = (const float*)d_in[2];
    const float* b_ih = (const float*)d_in[3];
    const float* b_hh = (const float*)d_in[4];
    const float* W_fc = (const float*)d_in[5];
    const float* b_fc = (const float*)d_in[6];
    float* out = (float*)d_out;

    lstm_encdec_kernel<<<NSEQ / SEQS_PER_WG, 512, 0, stream>>>(
        X, W_ih, W_hh, b_ih, b_hh, W_fc, b_fc, out);
}

// Round 3
// 280.003 us; speedup vs baseline: 1.2104x; 1.2104x over previous
//
#include <hip/hip_runtime.h>

#define SEQS_PER_WG 8
#define HID 128
#define NF 13
#define SLEN 128
#define NSEQ 2048
#define ZSTRIDE 232   // f16 elems per z row; 232*2=464B rows (16B aligned)

typedef _Float16 half8 __attribute__((ext_vector_type(8)));
typedef float floatx4 __attribute__((ext_vector_type(4)));

__device__ __forceinline__ float fast_rcp(float x) { return __builtin_amdgcn_rcpf(x); }
__device__ __forceinline__ float sigm(float x)  { return fast_rcp(1.0f + __expf(-x)); }
__device__ __forceinline__ float tanh_(float x) { return 1.0f - 2.0f * fast_rcp(1.0f + __expf(2.0f * x)); }

// v_permlane32_swap_b32: pr[0] = {lanes 0-31: a (own), lanes 32-63: b from lane-32}
// == "hi-half ? (lane-32's b) : (own a)" in one full-rate VALU op (no LDS pipe).
__device__ __forceinline__ float rowmerge(float a, float b) {
    auto pr = __builtin_amdgcn_permlane32_swap(__float_as_int(a), __float_as_int(b),
                                               false, false);
    return __int_as_float(pr[0]);
}

// ---- precompute: W_eff = W_hh + W_ih @ W_fc (f16), b_eff = b_ih+b_hh+W_ih@b_fc (f32)
// Decoder recurrence for t>=1 never needs x: x_{t+1} = h_{t+1}@W_fc^T + b_fc folds in.
__global__ __launch_bounds__(256)
void weff_kernel(const float* __restrict__ W_ih, const float* __restrict__ W_hh,
                 const float* __restrict__ b_ih, const float* __restrict__ b_hh,
                 const float* __restrict__ W_fc, const float* __restrict__ b_fc,
                 _Float16* __restrict__ w_eff, float* __restrict__ b_eff)
{
    const int idx = blockIdx.x * 256 + threadIdx.x;   // 4H*H = 65536 total
    const int n = idx >> 7, k = idx & 127;
    float s = W_hh[n * HID + k];
    #pragma unroll
    for (int f = 0; f < NF; ++f) s += W_ih[n * NF + f] * W_fc[f * HID + k];
    w_eff[n * HID + k] = (_Float16)s;
    if (k == 0) {
        float bb = b_ih[n] + b_hh[n];
        #pragma unroll
        for (int f = 0; f < NF; ++f) bb += W_ih[n * NF + f] * b_fc[f];
        b_eff[n] = bb;
    }
}

__global__ __launch_bounds__(512, 2)
void lstm_encdec_kernel(const float* __restrict__ X,
                        const float* __restrict__ W_ih,
                        const float* __restrict__ W_hh,
                        const float* __restrict__ b_ih,
                        const float* __restrict__ b_hh,
                        const float* __restrict__ W_fc,
                        const float* __restrict__ b_fc,
                        const _Float16* __restrict__ w_eff,
                        const float* __restrict__ b_eff,
                        float* __restrict__ out)
{
    // z = [h (128) | x (13, padded to 32)] per seq slot, fp16, double-buffered.
    // 16 row slots (A-operand reads rows 0..15); rows 8..15 stay zero.
    __shared__ _Float16 zbuf[2][16 * ZSTRIDE];

    const int tid  = threadIdx.x;
    const int wave = tid >> 6;            // 0..7
    const int lane = tid & 63;
    const int quad = lane >> 4;           // 0..3
    const int lcol = lane & 15;
    const int row0 = (quad & 1) * 4 + ((quad >> 1) ? 2 : 0); // first of 2 seq rows owned
    const int unit = wave * 16 + lcol;                       // hidden unit 0..127
    const int seq0 = blockIdx.x * SEQS_PER_WG;

    // ---- loop-invariant B fragments: gates[s][n] = sum_k z[s][k]*W[n][k], n = g*128+unit
    half8 Bf[4][5];
    floatx4 biasv[4];
    #pragma unroll
    for (int g = 0; g < 4; ++g) {
        const int n = g * HID + unit;
        #pragma unroll
        for (int ks = 0; ks < 4; ++ks) {              // h part
            const float* p = W_hh + n * HID + ks * 32 + quad * 8;
            half8 v;
            #pragma unroll
            for (int j = 0; j < 8; ++j) v[j] = (_Float16)p[j];
            Bf[g][ks] = v;
        }
        {                                             // x part (K-step 4)
            half8 v;
            #pragma unroll
            for (int j = 0; j < 8; ++j) {
                int kk = quad * 8 + j;
                v[j] = (kk < NF) ? (_Float16)W_ih[n * NF + kk] : (_Float16)0.0f;
            }
            Bf[g][4] = v;
        }
        float b = b_ih[n] + b_hh[n];
        biasv[g] = (floatx4){b, b, b, b};             // first MFMA's C operand
    }

    // W_fc fragments (wave 0 only)
    half8 Wfcf[4];
    floatx4 bfcv = (floatx4){0.0f, 0.0f, 0.0f, 0.0f};
    if (wave == 0) {
        #pragma unroll
        for (int ks = 0; ks < 4; ++ks) {
            half8 v;
            #pragma unroll
            for (int j = 0; j < 8; ++j)
                v[j] = (lcol < NF) ? (_Float16)W_fc[lcol * HID + ks * 32 + quad * 8 + j]
                                   : (_Float16)0.0f;
            Wfcf[ks] = v;
        }
        float b = (lcol < NF) ? b_fc[lcol] : 0.0f;
        bfcv = (floatx4){b, b, b, b};
    }

    // ---- init LDS: zero both buffers, then x_0
    for (int i = tid; i < 2 * 16 * ZSTRIDE; i += 512)
        ((_Float16*)zbuf)[i] = (_Float16)0.0f;
    __syncthreads();

    const bool xact = tid < SEQS_PER_WG * NF;         // 104 threads load x
    const int  xs = tid / NF, xf = tid % NF;
    const long xbase = (long)(seq0 + xs) * SLEN * NF + xf;
    if (xact) zbuf[0][xs * ZSTRIDE + HID + xf] = (_Float16)X[xbase];
    __syncthreads();

    float creg[2] = {0.0f, 0.0f};
    float h0 = 0.0f, h1 = 0.0f;
    int p = 0;

#define GATE_MFMA(NKS, ZR)                                                     \
    half8 a[5];                                                                \
    _Pragma("unroll")                                                          \
    for (int ks = 0; ks < (NKS); ++ks)                                         \
        a[ks] = *(const half8*)&(ZR)[lcol * ZSTRIDE + ks * 32 + quad * 8];     \
    floatx4 acc[4];                                                            \
    _Pragma("unroll")                                                          \
    for (int g = 0; g < 4; ++g)                                                \
        acc[g] = __builtin_amdgcn_mfma_f32_16x16x32_f16(a[0], Bf[g][0],        \
                                                        biasv[g], 0, 0, 0);    \
    _Pragma("unroll")                                                          \
    for (int ks = 1; ks < (NKS); ++ks)                                         \
        _Pragma("unroll")                                                      \
        for (int g = 0; g < 4; ++g)                                            \
            acc[g] = __builtin_amdgcn_mfma_f32_16x16x32_f16(a[ks], Bf[g][ks],  \
                                                            acc[g], 0, 0, 0);

#define GATES_EPILOGUE(ZW)                                                     \
    {                                                                          \
        float gv0[4], gv1[4];                                                  \
        _Pragma("unroll")                                                      \
        for (int g = 0; g < 4; ++g) {                                          \
            gv0[g] = rowmerge(acc[g][0], acc[g][2]);                           \
            gv1[g] = rowmerge(acc[g][1], acc[g][3]);                           \
        }                                                                      \
        float c0 = sigm(gv0[1]) * creg[0] + sigm(gv0[0]) * tanh_(gv0[2]);      \
        creg[0] = c0;                                                          \
        h0 = sigm(gv0[3]) * tanh_(c0);                                         \
        float c1 = sigm(gv1[1]) * creg[1] + sigm(gv1[0]) * tanh_(gv1[2]);      \
        creg[1] = c1;                                                          \
        h1 = sigm(gv1[3]) * tanh_(c1);                                         \
        (ZW)[(row0 + 0) * ZSTRIDE + unit] = (_Float16)h0;                      \
        (ZW)[(row0 + 1) * ZSTRIDE + unit] = (_Float16)h1;                      \
    }

    // ===================== encoder: 128 steps, 1 barrier/step =====================
    for (int t = 0; t < SLEN; ++t) {
        const int tn = (t + 1 < SLEN) ? t + 1 : SLEN - 1;
        float xpre = 0.0f;
        if (xact) xpre = X[xbase + tn * NF];

        const _Float16* zr = zbuf[p];
        _Float16* zw = zbuf[1 - p];

        GATE_MFMA(5, zr)
        GATES_EPILOGUE(zw)
        if (xact) zw[xs * ZSTRIDE + HID + xf] = (_Float16)xpre;

        __syncthreads();
        p ^= 1;
    }

    // embeddings = h_n
    out[(long)(seq0 + row0 + 0) * HID + unit] = h0;
    out[(long)(seq0 + row0 + 1) * HID + unit] = h1;

    float* dec = out + (long)NSEQ * HID;

    // ===================== decoder step 0: uses real x_127 (5 K-steps) ============
    {
        const _Float16* zr = zbuf[p];
        _Float16* zw = zbuf[1 - p];
        GATE_MFMA(5, zr)
        GATES_EPILOGUE(zw)
        __syncthreads();
        p ^= 1;
    }

    // ---- swap in precomputed effective weights (16 dwordx4 loads, no recompute) ----
    #pragma unroll
    for (int g = 0; g < 4; ++g) {
        const int n = g * HID + unit;
        #pragma unroll
        for (int ks = 0; ks < 4; ++ks)
            Bf[g][ks] = *(const half8*)&w_eff[n * HID + ks * 32 + quad * 8];
        const float bb = b_eff[n];
        biasv[g] = (floatx4){bb, bb, bb, bb};
    }

    // ============ decoder steps 1..127: 4 K-steps, 1 barrier, FC overlapped =======
    for (int t = 1; t < SLEN; ++t) {
        const _Float16* zr = zbuf[p];
        _Float16* zw = zbuf[1 - p];

        GATE_MFMA(4, zr)

        // wave 0: dec output for step t-1 = FC(h_t); h_t IS a[0..3] (reuse, no LDS)
        if (wave == 0) {
            floatx4 o = bfcv;
            #pragma unroll
            for (int ks = 0; ks < 4; ++ks)
                o = __builtin_amdgcn_mfma_f32_16x16x32_f16(a[ks], Wfcf[ks], o, 0, 0, 0);
            if (quad < 2 && lcol < NF) {
                #pragma unroll
                for (int r = 0; r < 4; ++r)
                    dec[(long)(seq0 + quad * 4 + r) * SLEN * NF + (t - 1) * NF + lcol] = o[r];
            }
        }

        GATES_EPILOGUE(zw)

        __syncthreads();
        p ^= 1;
    }

    // ---- final dec output: FC(h_128) from the last written buffer ----
    if (wave == 0) {
        const _Float16* zr = zbuf[p];
        half8 af[4];
        #pragma unroll
        for (int ks = 0; ks < 4; ++ks)
            af[ks] = *(const half8*)&zr[lcol * ZSTRIDE + ks * 32 + quad * 8];
        floatx4 o = bfcv;
        #pragma unroll
        for (int ks = 0; ks < 4; ++ks)
            o = __builtin_amdgcn_mfma_f32_16x16x32_f16(af[ks], Wfcf[ks], o, 0, 0, 0);
        if (quad < 2 && lcol < NF) {
            #pragma unroll
            for (int r = 0; r < 4; ++r)
                dec[(long)(seq0 + quad * 4 + r) * SLEN * NF + (SLEN - 1) * NF + lcol] = o[r];
        }
    }
}

extern "C" void kernel_launch(void* const* d_in, const int* in_sizes, int n_in,
                              void* d_out, int out_size, void* d_ws, size_t ws_size,
                              hipStream_t stream) {
    const float* X    = (const float*)d_in[0];
    const float* W_ih = (const float*)d_in[1];
    const float* W_hh = (const float*)d_in[2];
    const float* b_ih = (const float*)d_in[3];
    const float* b_hh = (const float*)d_in[4];
    const float* W_fc = (const float*)d_in[5];
    const float* b_fc = (const float*)d_in[6];
    float* out = (float*)d_out;

    _Float16* w_eff = (_Float16*)d_ws;                         // 4H*H f16 = 128 KiB
    float*    b_eff = (float*)((char*)d_ws + 4 * HID * HID * sizeof(_Float16));

    weff_kernel<<<(4 * HID * HID) / 256, 256, 0, stream>>>(
        W_ih, W_hh, b_ih, b_hh, W_fc, b_fc, w_eff, b_eff);

    lstm_encdec_kernel<<<NSEQ / SEQS_PER_WG, 512, 0, stream>>>(
        X, W_ih, W_hh, b_ih, b_hh, W_fc, b_fc, w_eff, b_eff, out);
}